// Round 9
// baseline (849.941 us; speedup 1.0000x reference)
//
#include <hip/hip_runtime.h>
#include <hip/hip_fp16.h>

// GCN 2-layer: N=100000, F=128 -> H=16 (relu) -> C=40, E=3200000.
//
// R10: eliminate the node-sorted es array entirely. R9 evidence: gathers sit
// exactly on the random-L2-txn floor (3.2M txn / 8 XCD / 4 per cy / 2.4GHz
// = 41.7us; k_gather2 = 40.7us with FETCH already L2-resident), so the only
// remaining lever is pass-count. k_csr's within-bucket sort (3.2M LDS-ranked
// stores + 12.8MB write + readback) is middleman work: aggregate DIRECTLY
// from the bucket-partitioned eb into a per-bucket LDS accumulator
// (256 nodes x 16 feat fp32 = 16KB, ds_add_f32 fire-and-forget). k_csr and
// es die; a tiny k_deg (bucket LDS histogram -> dinv) replaces rp/degree.
// eb moves to d_ws (k_agg2 reads eb while writing out -> d_out no longer
// usable as scratch for it).
//
// Pipeline: hist -> scanA -> scanB -> part -> deg -> gemm1 -> agg1 -> agg2
//
// Math: norm(s->d) = dinv[s]*dinv[d], self-loop norm = dinv[n]^2.
//   h1p = (x@W1)*dinv            (pre-scaled => no dinv[src] gather per edge)
//   agg1[n] = dinv[n]*(h1p[n] + sum_{s in in(n)} h1p[s])
//   r1p[n]  = relu(agg1[n]+b1)*dinv[n]          (fused in agg1 epilogue)
//   agg2[n] = dinv[n]*(r1p[n] + sum r1p[s])
//   out[n]  = agg2[n]@W2 + b2                   (fused in agg2 epilogue)

#define N_NODES 100000
#define F_IN    128
#define H_MID   16
#define C_OUT   40
#define N_EDGES 3200000

#define EC      8192                 // edges per chunk (k_hist / k_part block)
#define EBLK    391                  // ceil(N_EDGES / EC)
#define NBUK    391                  // buckets of 256 nodes: covers 0..100095
#define M_HIST  (NBUK * EBLK)        // 152881
#define NPART   299                  // ceil(M_HIST / 512)
#define SRC_MASK 0x1FFFF             // src < 100000 < 2^17
#define NSTRIDE 100352               // padded node stride

// ---------------- partition build (no global atomics) ----------------------

__global__ void __launch_bounds__(1024) k_hist(
    const int* __restrict__ dst, int* __restrict__ hist) {
    __shared__ int h[NBUK];
    int t = threadIdx.x, blk = blockIdx.x;
    for (int i = t; i < NBUK; i += 1024) h[i] = 0;
    __syncthreads();
#pragma unroll
    for (int i = 0; i < EC / 1024; ++i) {
        int e = blk * EC + i * 1024 + t;
        if (e < N_EDGES) atomicAdd(&h[__builtin_nontemporal_load(dst + e) >> 8], 1);
    }
    __syncthreads();
    for (int b = t; b < NBUK; b += 1024) hist[b * EBLK + blk] = h[b];
}

// block-local exclusive scan over the linear hist array (bucket-major)
__global__ void __launch_bounds__(512) k_scanA(int* __restrict__ hist,
                                               int* __restrict__ part) {
    __shared__ int s[512];
    int t = threadIdx.x;
    int i = blockIdx.x * 512 + t;
    int v = (i < M_HIST) ? hist[i] : 0;
    s[t] = v;
    __syncthreads();
    for (int off = 1; off < 512; off <<= 1) {
        int x = (t >= off) ? s[t - off] : 0;
        __syncthreads();
        s[t] += x;
        __syncthreads();
    }
    if (i < M_HIST) hist[i] = s[t] - v;
    if (t == 511) part[blockIdx.x] = s[511];
}

// exclusive scan of the NPART block sums; hist stays block-local-exclusive,
// consumers add part[idx>>9] on the fly.
__global__ void __launch_bounds__(512) k_scanB(int* __restrict__ part) {
    __shared__ int s[512];
    int t = threadIdx.x;
    int v = (t < NPART) ? part[t] : 0;
    s[t] = v;
    __syncthreads();
    for (int off = 1; off < 512; off <<= 1) {
        int x = (t >= off) ? s[t - off] : 0;
        __syncthreads();
        s[t] += x;
        __syncthreads();
    }
    if (t < NPART) part[t] = s[t] - v;
}

// partition edges into buckets via block-local LDS counting sort, then
// coalesced drain: eb[pos] = (loc8<<17)|src17.
__global__ void __launch_bounds__(1024) k_part(
    const int* __restrict__ src, const int* __restrict__ dst,
    const int* __restrict__ hist, const int* __restrict__ part,
    int* __restrict__ eb) {
    __shared__ int cnt[NBUK];
    __shared__ int scn[512];
    __shared__ int dlt[NBUK];
    __shared__ int cr[NBUK];
    __shared__ int sval[EC];
    __shared__ int spos[EC];
    int t = threadIdx.x, blk = blockIdx.x;
    for (int b = t; b < NBUK; b += 1024) cnt[b] = 0;
    __syncthreads();
    int e0 = blk * EC;
    int d[8], s[8], bk[8];
    bool val[8];
#pragma unroll
    for (int k = 0; k < 8; ++k) {
        int e = e0 + k * 1024 + t;
        val[k] = (e < N_EDGES);
        d[k] = val[k] ? __builtin_nontemporal_load(dst + e) : 0;
        s[k] = val[k] ? __builtin_nontemporal_load(src + e) : 0;
        bk[k] = d[k] >> 8;
    }
#pragma unroll
    for (int k = 0; k < 8; ++k)
        if (val[k]) atomicAdd(&cnt[bk[k]], 1);
    __syncthreads();
    if (t < 512) scn[t] = (t < NBUK) ? cnt[t] : 0;
    __syncthreads();
    for (int off = 1; off < 512; off <<= 1) {
        int x = 0;
        if (t < 512 && t >= off) x = scn[t - off];
        __syncthreads();
        if (t < 512) scn[t] += x;
        __syncthreads();
    }
    for (int b = t; b < NBUK; b += 1024) {
        int idx = b * EBLK + blk;
        int gb = hist[idx] + part[idx >> 9];   // global base of (b, blk) run
        int lb = scn[b] - cnt[b];              // local base (exclusive)
        dlt[b] = gb - lb;
        cr[b] = lb;
    }
    __syncthreads();
#pragma unroll
    for (int k = 0; k < 8; ++k) {
        if (val[k]) {
            int lr = atomicAdd(&cr[bk[k]], 1);           // LDS return-atomic
            sval[lr] = ((d[k] & 255) << 17) | s[k];
            spos[lr] = lr + dlt[bk[k]];
        }
    }
    __syncthreads();
    int n = (e0 + EC <= N_EDGES) ? EC : (N_EDGES - e0);
    for (int i = t; i < n; i += 1024)
        eb[spos[i]] = sval[i];                 // coalesced within ~21-edge runs
}

// per-bucket degree -> dinv (replaces rp/es machinery)
__global__ void __launch_bounds__(512) k_deg(
    const int* __restrict__ hist, const int* __restrict__ part,
    const int* __restrict__ eb, float* __restrict__ dinv) {
    __shared__ int deg[256];
    int b = blockIdx.x, t = threadIdx.x;
    int i0 = b * EBLK;
    int bb = hist[i0] + part[i0 >> 9];
    int bn = (b + 1 < NBUK) ? (hist[i0 + EBLK] + part[(i0 + EBLK) >> 9]) : N_EDGES;
    int ecnt = bn - bb;
    if (t < 256) deg[t] = 0;
    __syncthreads();
    for (int i = t; i < ecnt; i += 512)
        atomicAdd(&deg[__builtin_nontemporal_load(eb + bb + i) >> 17], 1);
    __syncthreads();
    if (t < 256) dinv[b * 256 + t] = rsqrtf(1.0f + (float)deg[t]);
}

// ---------------- dense kernels ------------------------

typedef float f4 __attribute__((ext_vector_type(4)));

// 16 nodes per block, 256 threads = 16 nodes x 16 out-features.
// h1p = fp16( (x@W1) * dinv[node] )
__global__ void __launch_bounds__(256) k_gemm1(
    const float* __restrict__ x, const float* __restrict__ W1,
    const float* __restrict__ dinv, __half* __restrict__ h1p) {
    __shared__ float w[F_IN * H_MID];   // 8 KB
    __shared__ float xs[16 * 132];      // padded rows: no 128-stride conflicts
    int t = threadIdx.x;
    for (int i = t; i < F_IN * H_MID; i += 256) w[i] = W1[i];
    int tile = blockIdx.x;              // 6250 tiles, exact
    const f4* xg = (const f4*)(x + (size_t)tile * 16 * F_IN);
    f4* xs4 = (f4*)xs;                  // row stride 33 float4
    for (int i = t; i < 512; i += 256) {
        int r = i >> 5, c4 = i & 31;
        xs4[r * 33 + c4] = __builtin_nontemporal_load(xg + r * 32 + c4);
    }
    __syncthreads();
    int node = t >> 4, j = t & 15;
    const float* xr = xs + node * 132;
    float acc = 0.f;
#pragma unroll 8
    for (int k = 0; k < F_IN; ++k) acc += xr[k] * w[k * H_MID + j];
    int g = tile * 16 + node;
    h1p[(size_t)g * H_MID + j] = __float2half(acc * dinv[g]);
}

// layer-1 aggregation straight from eb: LDS fp32 accumulator per bucket.
// r1p[n] = fp16( relu(dinv[n]*(h1p[n] + sum h1p[s]) + b1) * dinv[n] )
__global__ void __launch_bounds__(1024) k_agg1(
    const int* __restrict__ hist, const int* __restrict__ part,
    const int* __restrict__ eb, const float* __restrict__ dinv,
    const __half* __restrict__ h1p, const float* __restrict__ b1,
    __half* __restrict__ r1p) {
    __shared__ float acc[256 * H_MID];   // 16 KB
    int b = blockIdx.x, t = threadIdx.x;
    int i0 = b * EBLK;
    int bb = hist[i0] + part[i0 >> 9];
    int bn = (b + 1 < NBUK) ? (hist[i0 + EBLK] + part[(i0 + EBLK) >> 9]) : N_EDGES;
    int ecnt = bn - bb;
    // init with self-loop row (h1p pre-scaled): acc[i] = h1p[b*4096 + i]
    for (int i = t; i < 256 * H_MID; i += 1024)
        acc[i] = __half2float(h1p[(size_t)b * 4096 + i]);
    __syncthreads();
    int g = t >> 4, j = t & 15;          // 64 edge-groups x 16 features
    for (int base = 0; base < ecnt; base += 256) {
        int v[4];
        float hv[4];
#pragma unroll
        for (int k = 0; k < 4; ++k) {
            int ii = base + (k << 6) + g;
            v[k] = (ii < ecnt) ? __builtin_nontemporal_load(eb + bb + ii) : -1;
        }
#pragma unroll
        for (int k = 0; k < 4; ++k)
            if (v[k] >= 0) hv[k] = __half2float(h1p[(size_t)(v[k] & SRC_MASK) * H_MID + j]);
#pragma unroll
        for (int k = 0; k < 4; ++k)
            if (v[k] >= 0) atomicAdd(&acc[((v[k] >> 17) << 4) + j], hv[k]);  // ds_add_f32
    }
    __syncthreads();
    for (int i = t; i < 256 * H_MID; i += 1024) {
        int node = b * 256 + (i >> 4);
        float dv = dinv[node];
        float a = dv * acc[i];
        unsigned short o = __half_as_ushort(__float2half(fmaxf(a + b1[i & 15], 0.f) * dv));
        __builtin_nontemporal_store(o, (unsigned short*)(r1p + (size_t)b * 4096 + i));
    }
}

// layer-2 aggregation from eb + fused @W2 + b2 epilogue.
__global__ void __launch_bounds__(1024) k_agg2(
    const int* __restrict__ hist, const int* __restrict__ part,
    const int* __restrict__ eb, const float* __restrict__ dinv,
    const __half* __restrict__ r1p, const float* __restrict__ W2,
    const float* __restrict__ b2, float* __restrict__ out) {
    __shared__ float acc[256 * H_MID];   // 16 KB
    __shared__ float w2[H_MID * C_OUT];  // 2.5 KB
    __shared__ float b2l[C_OUT];
    int b = blockIdx.x, t = threadIdx.x;
    int i0 = b * EBLK;
    int bb = hist[i0] + part[i0 >> 9];
    int bn = (b + 1 < NBUK) ? (hist[i0 + EBLK] + part[(i0 + EBLK) >> 9]) : N_EDGES;
    int ecnt = bn - bb;
    for (int i = t; i < H_MID * C_OUT; i += 1024) w2[i] = W2[i];
    if (t < C_OUT) b2l[t] = b2[t];
    for (int i = t; i < 256 * H_MID; i += 1024)
        acc[i] = __half2float(r1p[(size_t)b * 4096 + i]);   // self loop
    __syncthreads();
    int g = t >> 4, j = t & 15;
    for (int base = 0; base < ecnt; base += 256) {
        int v[4];
        float hv[4];
#pragma unroll
        for (int k = 0; k < 4; ++k) {
            int ii = base + (k << 6) + g;
            v[k] = (ii < ecnt) ? __builtin_nontemporal_load(eb + bb + ii) : -1;
        }
#pragma unroll
        for (int k = 0; k < 4; ++k)
            if (v[k] >= 0) hv[k] = __half2float(r1p[(size_t)(v[k] & SRC_MASK) * H_MID + j]);
#pragma unroll
        for (int k = 0; k < 4; ++k)
            if (v[k] >= 0) atomicAdd(&acc[((v[k] >> 17) << 4) + j], hv[k]);  // ds_add_f32
    }
    __syncthreads();
    for (int i = t; i < 256 * H_MID; i += 1024)
        acc[i] *= dinv[b * 256 + (i >> 4)];                 // agg2 = dv * (...)
    __syncthreads();
    for (int idx = t; idx < 256 * C_OUT; idx += 1024) {
        int nd = idx / C_OUT, c = idx - nd * C_OUT;
        int node = b * 256 + nd;
        if (node < N_NODES) {
            float s = b2l[c];
#pragma unroll
            for (int jj = 0; jj < H_MID; ++jj) s += acc[nd * H_MID + jj] * w2[jj * C_OUT + c];
            __builtin_nontemporal_store(s, &out[(size_t)node * C_OUT + c]);
        }
    }
}

extern "C" void kernel_launch(void* const* d_in, const int* in_sizes, int n_in,
                              void* d_out, int out_size, void* d_ws, size_t ws_size,
                              hipStream_t stream) {
    const float* x  = (const float*)d_in[0];
    const int*   ei = (const int*)d_in[1];     // [2, E]: row 0 = src, row 1 = dst
    const float* W1 = (const float*)d_in[2];
    const float* b1 = (const float*)d_in[3];
    const float* W2 = (const float*)d_in[4];
    const float* b2 = (const float*)d_in[5];
    float* out = (float*)d_out;

    const int* src = ei;
    const int* dst = ei + N_EDGES;

    // ws layout (4B units), ~20.3 MiB -- all in d_ws (k_agg2 reads eb while
    // writing out, so d_out is NOT scratch anymore):
    //   dinv[100352] | h1p[100352*16 half] | r1p[same] | eb[3.2M] |
    //   hist[153088] | part[512]
    float* dinv = (float*)d_ws;
    __half* h1p = (__half*)(dinv + NSTRIDE);
    __half* r1p = h1p + (size_t)NSTRIDE * H_MID;
    int* eb     = (int*)(r1p + (size_t)NSTRIDE * H_MID);
    int* hist   = eb + N_EDGES;
    int* part   = hist + 153088;

    k_hist <<<EBLK, 1024, 0, stream>>>(dst, hist);
    k_scanA<<<NPART, 512, 0, stream>>>(hist, part);
    k_scanB<<<1, 512, 0, stream>>>(part);
    k_part <<<EBLK, 1024, 0, stream>>>(src, dst, hist, part, eb);
    k_deg  <<<NBUK, 512, 0, stream>>>(hist, part, eb, dinv);
    k_gemm1<<<N_NODES / 16, 256, 0, stream>>>(x, W1, dinv, h1p);
    k_agg1 <<<NBUK, 1024, 0, stream>>>(hist, part, eb, dinv, h1p, b1, r1p);
    k_agg2 <<<NBUK, 1024, 0, stream>>>(hist, part, eb, dinv, r1p, W2, b2, out);
}

// Round 10
// 236.654 us; speedup vs baseline: 3.5915x; 3.5915x over previous
//
#include <hip/hip_runtime.h>
#include <hip/hip_fp16.h>

// GCN 2-layer: N=100000, F=128 -> H=16 (relu) -> C=40, E=3200000.
//
// R11 = R9 skeleton (best-known-good, 235us) + gather1 fused into the
// within-bucket sort kernel.
// R10 post-mortem: LDS ds_add_f32 accumulation (k_agg*) = 9x regression --
// same-address atomic chains serialize (avg 32 adds/word). Per-node sums must
// come from sorted-order register accumulation. Reverted.
// R11 fusion: k_csr already builds the bucket's node-sorted edge list in LDS
// (esl). gather1 re-read that list from global. Now the same block, after the
// coalesced es drain (still needed by gather2), walks esl node-by-node with
// gather1's register accumulation and writes r1p. The random h1p loads (the
// 41.7us txn-floor cost) overlap the sort's LDS phases in ONE kernel.
// Half-bucket blocks (782 x 1024thr, filter on loc bit7) kill the 391-block
// tail. dinv/rp move to k_degrp (dinv must exist before gemm1).
//
// Math: norm(s->d) = dinv[s]*dinv[d], self-loop norm = dinv[n]^2.
//   h1p = (x@W1)*dinv            (pre-scaled => no dinv[src] gather per edge)
//   agg1[n] = dinv[n]*(h1p[n] + sum_{s in in(n)} h1p[s])
//   r1p[n]  = relu(agg1[n]+b1)*dinv[n]          (fused in csrg1 epilogue)
//   agg2[n] = dinv[n]*(r1p[n] + sum r1p[s])
//   out[n]  = agg2[n]@W2 + b2                   (fused in gather2 epilogue)

#define N_NODES 100000
#define F_IN    128
#define H_MID   16
#define C_OUT   40
#define N_EDGES 3200000

#define EC      8192                 // edges per chunk (k_hist / k_part block)
#define EBLK    391                  // ceil(N_EDGES / EC)
#define NBUK    391                  // buckets of 256 nodes: covers 0..100095
#define M_HIST  (NBUK * EBLK)        // 152881
#define NPART   299                  // ceil(M_HIST / 512)
#define SRC_MASK 0x1FFFF             // src < 100000 < 2^17
#define NSTRIDE 100352               // padded node stride
#define CAP_H   5632                 // half-bucket esl (mean 4096, sd ~64)

// ---------------- partition build (no global atomics) ----------------------

__global__ void __launch_bounds__(1024) k_hist(
    const int* __restrict__ dst, int* __restrict__ hist) {
    __shared__ int h[NBUK];
    int t = threadIdx.x, blk = blockIdx.x;
    for (int i = t; i < NBUK; i += 1024) h[i] = 0;
    __syncthreads();
#pragma unroll
    for (int i = 0; i < EC / 1024; ++i) {
        int e = blk * EC + i * 1024 + t;
        if (e < N_EDGES) atomicAdd(&h[__builtin_nontemporal_load(dst + e) >> 8], 1);
    }
    __syncthreads();
    for (int b = t; b < NBUK; b += 1024) hist[b * EBLK + blk] = h[b];
}

// block-local exclusive scan over the linear hist array (bucket-major)
__global__ void __launch_bounds__(512) k_scanA(int* __restrict__ hist,
                                               int* __restrict__ part) {
    __shared__ int s[512];
    int t = threadIdx.x;
    int i = blockIdx.x * 512 + t;
    int v = (i < M_HIST) ? hist[i] : 0;
    s[t] = v;
    __syncthreads();
    for (int off = 1; off < 512; off <<= 1) {
        int x = (t >= off) ? s[t - off] : 0;
        __syncthreads();
        s[t] += x;
        __syncthreads();
    }
    if (i < M_HIST) hist[i] = s[t] - v;
    if (t == 511) part[blockIdx.x] = s[511];
}

// exclusive scan of the NPART block sums; hist stays block-local-exclusive,
// consumers add part[idx>>9] on the fly.
__global__ void __launch_bounds__(512) k_scanB(int* __restrict__ part) {
    __shared__ int s[512];
    int t = threadIdx.x;
    int v = (t < NPART) ? part[t] : 0;
    s[t] = v;
    __syncthreads();
    for (int off = 1; off < 512; off <<= 1) {
        int x = (t >= off) ? s[t - off] : 0;
        __syncthreads();
        s[t] += x;
        __syncthreads();
    }
    if (t < NPART) part[t] = s[t] - v;
}

// partition edges into buckets via block-local LDS counting sort, then
// coalesced drain: eb[pos] = (loc8<<17)|src17.   (R9, proven)
__global__ void __launch_bounds__(1024) k_part(
    const int* __restrict__ src, const int* __restrict__ dst,
    const int* __restrict__ hist, const int* __restrict__ part,
    int* __restrict__ eb) {
    __shared__ int cnt[NBUK];
    __shared__ int scn[512];
    __shared__ int dlt[NBUK];
    __shared__ int cr[NBUK];
    __shared__ int sval[EC];
    __shared__ int spos[EC];
    int t = threadIdx.x, blk = blockIdx.x;
    for (int b = t; b < NBUK; b += 1024) cnt[b] = 0;
    __syncthreads();
    int e0 = blk * EC;
    int d[8], s[8], bk[8];
    bool val[8];
#pragma unroll
    for (int k = 0; k < 8; ++k) {
        int e = e0 + k * 1024 + t;
        val[k] = (e < N_EDGES);
        d[k] = val[k] ? __builtin_nontemporal_load(dst + e) : 0;
        s[k] = val[k] ? __builtin_nontemporal_load(src + e) : 0;
        bk[k] = d[k] >> 8;
    }
#pragma unroll
    for (int k = 0; k < 8; ++k)
        if (val[k]) atomicAdd(&cnt[bk[k]], 1);
    __syncthreads();
    if (t < 512) scn[t] = (t < NBUK) ? cnt[t] : 0;
    __syncthreads();
    for (int off = 1; off < 512; off <<= 1) {
        int x = 0;
        if (t < 512 && t >= off) x = scn[t - off];
        __syncthreads();
        if (t < 512) scn[t] += x;
        __syncthreads();
    }
    for (int b = t; b < NBUK; b += 1024) {
        int idx = b * EBLK + blk;
        int gb = hist[idx] + part[idx >> 9];   // global base of (b, blk) run
        int lb = scn[b] - cnt[b];              // local base (exclusive)
        dlt[b] = gb - lb;
        cr[b] = lb;
    }
    __syncthreads();
#pragma unroll
    for (int k = 0; k < 8; ++k) {
        if (val[k]) {
            int lr = atomicAdd(&cr[bk[k]], 1);           // LDS return-atomic
            sval[lr] = ((d[k] & 255) << 17) | s[k];
            spos[lr] = lr + dlt[bk[k]];
        }
    }
    __syncthreads();
    int n = (e0 + EC <= N_EDGES) ? EC : (N_EDGES - e0);
    for (int i = t; i < n; i += 1024)
        eb[spos[i]] = sval[i];                 // coalesced within ~21-edge runs
}

// per-bucket degree -> rp (global node-sorted bases) + dinv.
__global__ void __launch_bounds__(512) k_degrp(
    const int* __restrict__ hist, const int* __restrict__ part,
    const int* __restrict__ eb, int* __restrict__ rp,
    float* __restrict__ dinv) {
    __shared__ int deg[256], scn[256];
    int b = blockIdx.x, t = threadIdx.x;
    int i0 = b * EBLK;
    int bb = hist[i0] + part[i0 >> 9];
    int bn = (b + 1 < NBUK) ? (hist[i0 + EBLK] + part[(i0 + EBLK) >> 9]) : N_EDGES;
    int ecnt = bn - bb;
    if (t < 256) deg[t] = 0;
    __syncthreads();
    for (int i = t; i < ecnt; i += 512)
        atomicAdd(&deg[__builtin_nontemporal_load(eb + bb + i) >> 17], 1);
    __syncthreads();
    if (t < 256) scn[t] = deg[t];
    __syncthreads();
    for (int off = 1; off < 256; off <<= 1) {
        int x = (t < 256 && t >= off) ? scn[t - off] : 0;
        __syncthreads();
        if (t < 256) scn[t] += x;
        __syncthreads();
    }
    if (t < 256) {
        int ex = scn[t] - deg[t];              // exclusive within bucket
        int node = b * 256 + t;                // < 100096
        rp[node] = bb + ex;                    // rp[100000] == N_EDGES naturally
        dinv[node] = rsqrtf(1.0f + (float)deg[t]);
    }
}

// ---------------- dense kernels ------------------------

typedef float f4 __attribute__((ext_vector_type(4)));

// 16 nodes per block, 256 threads = 16 nodes x 16 out-features.
// h1p = fp16( (x@W1) * dinv[node] )
__global__ void __launch_bounds__(256) k_gemm1(
    const float* __restrict__ x, const float* __restrict__ W1,
    const float* __restrict__ dinv, __half* __restrict__ h1p) {
    __shared__ float w[F_IN * H_MID];   // 8 KB
    __shared__ float xs[16 * 132];      // padded rows: no 128-stride conflicts
    int t = threadIdx.x;
    for (int i = t; i < F_IN * H_MID; i += 256) w[i] = W1[i];
    int tile = blockIdx.x;              // 6250 tiles, exact
    const f4* xg = (const f4*)(x + (size_t)tile * 16 * F_IN);
    f4* xs4 = (f4*)xs;                  // row stride 33 float4
    for (int i = t; i < 512; i += 256) {
        int r = i >> 5, c4 = i & 31;
        xs4[r * 33 + c4] = __builtin_nontemporal_load(xg + r * 32 + c4);
    }
    __syncthreads();
    int node = t >> 4, j = t & 15;
    const float* xr = xs + node * 132;
    float acc = 0.f;
#pragma unroll 8
    for (int k = 0; k < F_IN; ++k) acc += xr[k] * w[k * H_MID + j];
    int g = tile * 16 + node;
    h1p[(size_t)g * H_MID + j] = __float2half(acc * dinv[g]);
}

// FUSED: half-bucket node-sort (LDS) + coalesced es drain + gather1.
// r1p[n] = fp16( relu(dinv[n]*(h1p[n] + sum h1p[s]) + b1) * dinv[n] )
__global__ void __launch_bounds__(1024) k_csrg1(
    const int* __restrict__ hist, const int* __restrict__ part,
    const int* __restrict__ eb, const int* __restrict__ rp,
    const float* __restrict__ dinv, const __half* __restrict__ h1p,
    const float* __restrict__ b1, int* __restrict__ es,
    __half* __restrict__ r1p) {
    __shared__ int base[129];
    __shared__ int cw[128];
    __shared__ int esl[CAP_H];
    int bh = blockIdx.x;               // 0..781
    int b = bh >> 1, hi = bh & 1;
    int t = threadIdx.x;
    int i0 = b * EBLK;
    int bb = hist[i0] + part[i0 >> 9];
    int bn = (b + 1 < NBUK) ? (hist[i0 + EBLK] + part[(i0 + EBLK) >> 9]) : N_EDGES;
    int ecnt = bn - bb;
    int n0 = b * 256 + hi * 128;       // first node of this half
    if (t < 128) {
        int lb = rp[n0 + t] - bb;      // bucket-local segment start
        base[t] = lb;
        cw[t] = lb;
    }
    if (t == 128) base[128] = hi ? ecnt : (rp[b * 256 + 128] - bb);
    __syncthreads();
    int h0 = base[0];
    int hcnt = base[128] - h0;
    int g = t >> 4, j = t & 15;        // 64 groups x 16 feature-lanes
    if (hcnt <= CAP_H) {
        // phase 1: rank-scatter this half's edges into node-sorted esl
        for (int i = t; i < ecnt; i += 1024) {
            int v = __builtin_nontemporal_load(eb + bb + i);
            int loc = v >> 17;
            if ((loc >> 7) == hi) {
                int r = atomicAdd(&cw[loc & 127], 1);    // LDS return-atomic
                esl[r - h0] = v & SRC_MASK;
            }
        }
        __syncthreads();
        // phase 2: coalesced drain to es (for gather2)
        for (int i = t; i < hcnt; i += 1024)
            __builtin_nontemporal_store(esl[i], es + bb + h0 + i);
        // phase 3: gather1 from esl (register accumulation, node-sorted)
        for (int nd = g; nd < 128; nd += 64) {
            int node = n0 + nd;
            if (node >= N_NODES) continue;
            float dv = dinv[node];
            int beg = base[nd] - h0, end = base[nd + 1] - h0;
            float acc = __half2float(h1p[(size_t)node * H_MID + j]);  // self loop
            int e = beg;
            for (; e + 8 <= end; e += 8) {
                int s0 = esl[e],     s1 = esl[e + 1], s2 = esl[e + 2], s3 = esl[e + 3];
                int s4 = esl[e + 4], s5 = esl[e + 5], s6 = esl[e + 6], s7 = esl[e + 7];
                acc += __half2float(h1p[(size_t)s0 * H_MID + j])
                     + __half2float(h1p[(size_t)s1 * H_MID + j])
                     + __half2float(h1p[(size_t)s2 * H_MID + j])
                     + __half2float(h1p[(size_t)s3 * H_MID + j])
                     + __half2float(h1p[(size_t)s4 * H_MID + j])
                     + __half2float(h1p[(size_t)s5 * H_MID + j])
                     + __half2float(h1p[(size_t)s6 * H_MID + j])
                     + __half2float(h1p[(size_t)s7 * H_MID + j]);
            }
            for (; e < end; ++e) acc += __half2float(h1p[(size_t)esl[e] * H_MID + j]);
            float a = dv * acc;
            unsigned short o = __half_as_ushort(__float2half(fmaxf(a + b1[j], 0.f) * dv));
            __builtin_nontemporal_store(o, (unsigned short*)(r1p + (size_t)node * H_MID + j));
        }
    } else {
        // statistically-unreachable fallback (hcnt > +16 sigma): global scatter
        for (int i = t; i < ecnt; i += 1024) {
            int v = eb[bb + i];
            int loc = v >> 17;
            if ((loc >> 7) == hi) {
                int r = atomicAdd(&cw[loc & 127], 1);
                es[bb + r] = v & SRC_MASK;
            }
        }
        __threadfence_block();
        __syncthreads();
        for (int nd = g; nd < 128; nd += 64) {
            int node = n0 + nd;
            if (node >= N_NODES) continue;
            float dv = dinv[node];
            int beg = bb + base[nd], end = bb + base[nd + 1];
            float acc = __half2float(h1p[(size_t)node * H_MID + j]);
            for (int e = beg; e < end; ++e)
                acc += __half2float(h1p[(size_t)es[e] * H_MID + j]);
            float a = dv * acc;
            unsigned short o = __half_as_ushort(__float2half(fmaxf(a + b1[j], 0.f) * dv));
            __builtin_nontemporal_store(o, (unsigned short*)(r1p + (size_t)node * H_MID + j));
        }
    }
}

// gather layer 2 + fused @W2 + b2 epilogue (LDS).  (R9, proven)
__global__ void __launch_bounds__(256) k_gather2(
    const int* __restrict__ rp, const int* __restrict__ es,
    const float* __restrict__ dinv, const __half* __restrict__ r1p,
    const float* __restrict__ W2, const float* __restrict__ b2,
    float* __restrict__ out) {
    __shared__ float w2[H_MID * C_OUT];   // 640
    __shared__ float a2[16 * 17];         // padded
    int t = threadIdx.x;
    for (int i = t; i < H_MID * C_OUT; i += 256) w2[i] = W2[i];
    int tile = blockIdx.x;
    int node = tile * 16 + (t >> 4), j = t & 15;
    float dv = dinv[node];
    int beg = rp[node], end = rp[node + 1];
    float acc = __half2float(r1p[(size_t)node * H_MID + j]);  // self loop
    int e = beg;
    for (; e + 8 <= end; e += 8) {
        int s0 = es[e],     s1 = es[e + 1], s2 = es[e + 2], s3 = es[e + 3];
        int s4 = es[e + 4], s5 = es[e + 5], s6 = es[e + 6], s7 = es[e + 7];
        acc += __half2float(r1p[(size_t)s0 * H_MID + j])
             + __half2float(r1p[(size_t)s1 * H_MID + j])
             + __half2float(r1p[(size_t)s2 * H_MID + j])
             + __half2float(r1p[(size_t)s3 * H_MID + j])
             + __half2float(r1p[(size_t)s4 * H_MID + j])
             + __half2float(r1p[(size_t)s5 * H_MID + j])
             + __half2float(r1p[(size_t)s6 * H_MID + j])
             + __half2float(r1p[(size_t)s7 * H_MID + j]);
    }
    for (; e < end; ++e) acc += __half2float(r1p[(size_t)es[e] * H_MID + j]);
    a2[(t >> 4) * 17 + j] = dv * acc;
    __syncthreads();
    for (int idx = t; idx < 16 * C_OUT; idx += 256) {
        int nd = idx / C_OUT, c = idx - nd * C_OUT;
        float s = b2[c];
#pragma unroll
        for (int jj = 0; jj < H_MID; ++jj) s += a2[nd * 17 + jj] * w2[jj * C_OUT + c];
        __builtin_nontemporal_store(s, &out[((size_t)tile * 16 + nd) * C_OUT + c]);
    }
}

extern "C" void kernel_launch(void* const* d_in, const int* in_sizes, int n_in,
                              void* d_out, int out_size, void* d_ws, size_t ws_size,
                              hipStream_t stream) {
    const float* x  = (const float*)d_in[0];
    const int*   ei = (const int*)d_in[1];     // [2, E]: row 0 = src, row 1 = dst
    const float* W1 = (const float*)d_in[2];
    const float* b1 = (const float*)d_in[3];
    const float* W2 = (const float*)d_in[4];
    const float* b2 = (const float*)d_in[5];
    float* out = (float*)d_out;

    const int* src = ei;
    const int* dst = ei + N_EDGES;

    // ws layout (4B units), ~20 MiB:
    //   rp[100352] | dinv[100352] | es[3.2M] | h1p[NSTRIDE*16 half] | r1p[same]
    // d_out (16MB) is scratch until k_gather2 (sole writer of out):
    //   eb[3.2M] (12.8MB) | hist[153088] (0.61MB) | part[512]
    // (eb/hist/part last read by k_csrg1, which runs before k_gather2.)
    int* rp     = (int*)d_ws;
    float* dinv = (float*)(rp + NSTRIDE);
    int* es     = (int*)(dinv + NSTRIDE);
    __half* h1p = (__half*)(es + N_EDGES);
    __half* r1p = h1p + (size_t)NSTRIDE * H_MID;

    int* eb   = (int*)d_out;
    int* hist = eb + N_EDGES;
    int* part = hist + 153088;

    k_hist <<<EBLK, 1024, 0, stream>>>(dst, hist);
    k_scanA<<<NPART, 512, 0, stream>>>(hist, part);
    k_scanB<<<1, 512, 0, stream>>>(part);
    k_part <<<EBLK, 1024, 0, stream>>>(src, dst, hist, part, eb);
    k_degrp<<<NBUK, 512, 0, stream>>>(hist, part, eb, rp, dinv);
    k_gemm1<<<N_NODES / 16, 256, 0, stream>>>(x, W1, dinv, h1p);
    k_csrg1<<<NBUK * 2, 1024, 0, stream>>>(hist, part, eb, rp, dinv, h1p, b1, es, r1p);
    k_gather2<<<N_NODES / 16, 256, 0, stream>>>(rp, es, dinv, r1p, W2, b2, out);
}

// Round 11
// 228.492 us; speedup vs baseline: 3.7198x; 1.0357x over previous
//
#include <hip/hip_runtime.h>
#include <hip/hip_fp16.h>

// GCN 2-layer: N=100000, F=128 -> H=16 (relu) -> C=40, E=3200000.
//
// R12: both layers as fused per-bucket {LDS rank-sort + register gather}.
// R11 evidence: k_csrg1 (sort+gather1 fused) ran UNDER the 43us txn floor --
// the LDS sort hides completely under the E random-load latency. So:
//  - 128-node buckets end-to-end (NBUK=782): every fused block reads exactly
//    its own eb segment once (R11's half-blocks read the bucket twice).
//  - es eliminated: layer 2 = k_csrg2 (sort + gather + @W2 epilogue) straight
//    from eb. Saves es 12.8MB write + 12.8MB read.
//  - eb moves to d_ws (csrg2 reads it while writing out).
// R10 lesson kept: per-node sums are register accumulation over node-sorted
// edges, never scattered LDS atomic adds.
//
// Math: norm(s->d) = dinv[s]*dinv[d], self-loop norm = dinv[n]^2.
//   h1p = (x@W1)*dinv            (pre-scaled => no dinv[src] gather per edge)
//   agg1[n] = dinv[n]*(h1p[n] + sum_{s in in(n)} h1p[s])
//   r1p[n]  = relu(agg1[n]+b1)*dinv[n]          (fused in csrg1 epilogue)
//   agg2[n] = dinv[n]*(r1p[n] + sum r1p[s])
//   out[n]  = agg2[n]@W2 + b2                   (fused in csrg2 epilogue)

#define N_NODES 100000
#define F_IN    128
#define H_MID   16
#define C_OUT   40
#define N_EDGES 3200000

#define EC      8192                 // edges per chunk (k_hist / k_part block)
#define EBLK    391                  // ceil(N_EDGES / EC)
#define NBUK    782                  // buckets of 128 nodes: covers 0..100095
#define M_HIST  (NBUK * EBLK)        // 305762
#define NPART   598                  // ceil(M_HIST / 512)
#define SRC_MASK 0x1FFFF             // src < 100000 < 2^17
#define NSTRIDE 100352               // padded node stride
#define CAP_H   5632                 // per-bucket esl (mean 4096, sd ~64: +24 sigma)

// ---------------- partition build (no global atomics) ----------------------

__global__ void __launch_bounds__(1024) k_hist(
    const int* __restrict__ dst, int* __restrict__ hist) {
    __shared__ int h[NBUK];
    int t = threadIdx.x, blk = blockIdx.x;
    for (int i = t; i < NBUK; i += 1024) h[i] = 0;
    __syncthreads();
#pragma unroll
    for (int i = 0; i < EC / 1024; ++i) {
        int e = blk * EC + i * 1024 + t;
        if (e < N_EDGES) atomicAdd(&h[__builtin_nontemporal_load(dst + e) >> 7], 1);
    }
    __syncthreads();
    for (int b = t; b < NBUK; b += 1024) hist[b * EBLK + blk] = h[b];
}

// block-local exclusive scan over the linear hist array (bucket-major)
__global__ void __launch_bounds__(512) k_scanA(int* __restrict__ hist,
                                               int* __restrict__ part) {
    __shared__ int s[512];
    int t = threadIdx.x;
    int i = blockIdx.x * 512 + t;
    int v = (i < M_HIST) ? hist[i] : 0;
    s[t] = v;
    __syncthreads();
    for (int off = 1; off < 512; off <<= 1) {
        int x = (t >= off) ? s[t - off] : 0;
        __syncthreads();
        s[t] += x;
        __syncthreads();
    }
    if (i < M_HIST) hist[i] = s[t] - v;
    if (t == 511) part[blockIdx.x] = s[511];
}

// exclusive scan of the NPART block sums; hist stays block-local-exclusive,
// consumers add part[idx>>9] on the fly.
__global__ void __launch_bounds__(1024) k_scanB(int* __restrict__ part) {
    __shared__ int s[1024];
    int t = threadIdx.x;
    int v = (t < NPART) ? part[t] : 0;
    s[t] = v;
    __syncthreads();
    for (int off = 1; off < 1024; off <<= 1) {
        int x = (t >= off) ? s[t - off] : 0;
        __syncthreads();
        s[t] += x;
        __syncthreads();
    }
    if (t < NPART) part[t] = s[t] - v;
}

// partition edges into 128-node buckets via block-local LDS counting sort,
// then coalesced drain: eb[pos] = (loc7<<17)|src17.
__global__ void __launch_bounds__(1024) k_part(
    const int* __restrict__ src, const int* __restrict__ dst,
    const int* __restrict__ hist, const int* __restrict__ part,
    int* __restrict__ eb) {
    __shared__ int cnt[NBUK];
    __shared__ int scn[1024];
    __shared__ int dlt[NBUK];
    __shared__ int cr[NBUK];
    __shared__ int sval[EC];
    __shared__ int spos[EC];
    int t = threadIdx.x, blk = blockIdx.x;
    for (int b = t; b < NBUK; b += 1024) cnt[b] = 0;
    __syncthreads();
    int e0 = blk * EC;
    int d[8], s[8], bk[8];
    bool val[8];
#pragma unroll
    for (int k = 0; k < 8; ++k) {
        int e = e0 + k * 1024 + t;
        val[k] = (e < N_EDGES);
        d[k] = val[k] ? __builtin_nontemporal_load(dst + e) : 0;
        s[k] = val[k] ? __builtin_nontemporal_load(src + e) : 0;
        bk[k] = d[k] >> 7;
    }
#pragma unroll
    for (int k = 0; k < 8; ++k)
        if (val[k]) atomicAdd(&cnt[bk[k]], 1);
    __syncthreads();
    scn[t] = (t < NBUK) ? cnt[t] : 0;
    __syncthreads();
    for (int off = 1; off < 1024; off <<= 1) {
        int x = (t >= off) ? scn[t - off] : 0;
        __syncthreads();
        scn[t] += x;
        __syncthreads();
    }
    for (int b = t; b < NBUK; b += 1024) {
        int idx = b * EBLK + blk;
        int gb = hist[idx] + part[idx >> 9];   // global base of (b, blk) run
        int lb = scn[b] - cnt[b];              // local base (exclusive)
        dlt[b] = gb - lb;
        cr[b] = lb;
    }
    __syncthreads();
#pragma unroll
    for (int k = 0; k < 8; ++k) {
        if (val[k]) {
            int lr = atomicAdd(&cr[bk[k]], 1);           // LDS return-atomic
            sval[lr] = ((d[k] & 127) << 17) | s[k];
            spos[lr] = lr + dlt[bk[k]];
        }
    }
    __syncthreads();
    int n = (e0 + EC <= N_EDGES) ? EC : (N_EDGES - e0);
    for (int i = t; i < n; i += 1024)
        eb[spos[i]] = sval[i];                 // coalesced within ~10-edge runs
}

// per-bucket degree -> rp (global node-sorted bases) + dinv.
__global__ void __launch_bounds__(512) k_degrp(
    const int* __restrict__ hist, const int* __restrict__ part,
    const int* __restrict__ eb, int* __restrict__ rp,
    float* __restrict__ dinv) {
    __shared__ int deg[128], scn[128];
    int b = blockIdx.x, t = threadIdx.x;
    int i0 = b * EBLK;
    int bb = hist[i0] + part[i0 >> 9];
    int bn = (b + 1 < NBUK) ? (hist[i0 + EBLK] + part[(i0 + EBLK) >> 9]) : N_EDGES;
    int ecnt = bn - bb;
    if (t < 128) deg[t] = 0;
    __syncthreads();
    for (int i = t; i < ecnt; i += 512)
        atomicAdd(&deg[__builtin_nontemporal_load(eb + bb + i) >> 17], 1);
    __syncthreads();
    if (t < 128) scn[t] = deg[t];
    __syncthreads();
    for (int off = 1; off < 128; off <<= 1) {
        int x = (t < 128 && t >= off) ? scn[t - off] : 0;
        __syncthreads();
        if (t < 128) scn[t] += x;
        __syncthreads();
    }
    if (t < 128) {
        int ex = scn[t] - deg[t];              // exclusive within bucket
        int node = b * 128 + t;                // < 100096
        rp[node] = bb + ex;
        dinv[node] = rsqrtf(1.0f + (float)deg[t]);
    }
}

// ---------------- dense kernels ------------------------

typedef float f4 __attribute__((ext_vector_type(4)));

// 16 nodes per block, 256 threads = 16 nodes x 16 out-features.
// h1p = fp16( (x@W1) * dinv[node] )
__global__ void __launch_bounds__(256) k_gemm1(
    const float* __restrict__ x, const float* __restrict__ W1,
    const float* __restrict__ dinv, __half* __restrict__ h1p) {
    __shared__ float w[F_IN * H_MID];   // 8 KB
    __shared__ float xs[16 * 132];      // padded rows: no 128-stride conflicts
    int t = threadIdx.x;
    for (int i = t; i < F_IN * H_MID; i += 256) w[i] = W1[i];
    int tile = blockIdx.x;              // 6250 tiles, exact
    const f4* xg = (const f4*)(x + (size_t)tile * 16 * F_IN);
    f4* xs4 = (f4*)xs;                  // row stride 33 float4
    for (int i = t; i < 512; i += 256) {
        int r = i >> 5, c4 = i & 31;
        xs4[r * 33 + c4] = __builtin_nontemporal_load(xg + r * 32 + c4);
    }
    __syncthreads();
    int node = t >> 4, j = t & 15;
    const float* xr = xs + node * 132;
    float acc = 0.f;
#pragma unroll 8
    for (int k = 0; k < F_IN; ++k) acc += xr[k] * w[k * H_MID + j];
    int g = tile * 16 + node;
    h1p[(size_t)g * H_MID + j] = __float2half(acc * dinv[g]);
}

// FUSED layer 1: per-bucket LDS rank-sort + register gather + relu/bias.
// r1p[n] = fp16( relu(dinv[n]*(h1p[n] + sum h1p[s]) + b1) * dinv[n] )
__global__ void __launch_bounds__(1024) k_csrg1(
    const int* __restrict__ hist, const int* __restrict__ part,
    const int* __restrict__ eb, const int* __restrict__ rp,
    const float* __restrict__ dinv, const __half* __restrict__ h1p,
    const float* __restrict__ b1, __half* __restrict__ r1p) {
    __shared__ int base[129];
    __shared__ int cw[128];
    __shared__ int esl[CAP_H];
    int b = blockIdx.x, t = threadIdx.x;
    int i0 = b * EBLK;
    int bb = hist[i0] + part[i0 >> 9];
    int bn = (b + 1 < NBUK) ? (hist[i0 + EBLK] + part[(i0 + EBLK) >> 9]) : N_EDGES;
    int ecnt = bn - bb;
    int n0 = b * 128;
    if (t < 128) {
        int lb = rp[n0 + t] - bb;      // bucket-local segment start
        base[t] = lb;
        cw[t] = lb;
    }
    if (t == 128) base[128] = ecnt;
    __syncthreads();
    int g = t >> 4, j = t & 15;        // 64 groups x 16 feature-lanes
    if (ecnt <= CAP_H) {
        for (int i = t; i < ecnt; i += 1024) {          // rank-sort into esl
            int v = __builtin_nontemporal_load(eb + bb + i);
            int r = atomicAdd(&cw[v >> 17], 1);          // LDS return-atomic
            esl[r] = v & SRC_MASK;
        }
        __syncthreads();
        for (int nd = g; nd < 128; nd += 64) {           // register gather
            int node = n0 + nd;
            if (node >= N_NODES) continue;
            float dv = dinv[node];
            int beg = base[nd], end = base[nd + 1];
            float acc = __half2float(h1p[(size_t)node * H_MID + j]);  // self loop
            int e = beg;
            for (; e + 8 <= end; e += 8) {
                int s0 = esl[e],     s1 = esl[e + 1], s2 = esl[e + 2], s3 = esl[e + 3];
                int s4 = esl[e + 4], s5 = esl[e + 5], s6 = esl[e + 6], s7 = esl[e + 7];
                acc += __half2float(h1p[(size_t)s0 * H_MID + j])
                     + __half2float(h1p[(size_t)s1 * H_MID + j])
                     + __half2float(h1p[(size_t)s2 * H_MID + j])
                     + __half2float(h1p[(size_t)s3 * H_MID + j])
                     + __half2float(h1p[(size_t)s4 * H_MID + j])
                     + __half2float(h1p[(size_t)s5 * H_MID + j])
                     + __half2float(h1p[(size_t)s6 * H_MID + j])
                     + __half2float(h1p[(size_t)s7 * H_MID + j]);
            }
            for (; e < end; ++e) acc += __half2float(h1p[(size_t)esl[e] * H_MID + j]);
            float a = dv * acc;
            unsigned short o = __half_as_ushort(__float2half(fmaxf(a + b1[j], 0.f) * dv));
            __builtin_nontemporal_store(o, (unsigned short*)(r1p + (size_t)node * H_MID + j));
        }
    } else {
        // statistically-unreachable fallback (ecnt > +24 sigma): O(n*e) scan
        for (int nd = g; nd < 128; nd += 64) {
            int node = n0 + nd;
            if (node >= N_NODES) continue;
            float dv = dinv[node];
            float acc = __half2float(h1p[(size_t)node * H_MID + j]);
            for (int i = 0; i < ecnt; ++i) {
                int v = eb[bb + i];
                if ((v >> 17) == nd)
                    acc += __half2float(h1p[(size_t)(v & SRC_MASK) * H_MID + j]);
            }
            float a = dv * acc;
            unsigned short o = __half_as_ushort(__float2half(fmaxf(a + b1[j], 0.f) * dv));
            __builtin_nontemporal_store(o, (unsigned short*)(r1p + (size_t)node * H_MID + j));
        }
    }
}

// FUSED layer 2: per-bucket LDS rank-sort + register gather + @W2 + b2.
__global__ void __launch_bounds__(1024) k_csrg2(
    const int* __restrict__ hist, const int* __restrict__ part,
    const int* __restrict__ eb, const int* __restrict__ rp,
    const float* __restrict__ dinv, const __half* __restrict__ r1p,
    const float* __restrict__ W2, const float* __restrict__ b2,
    float* __restrict__ out) {
    __shared__ int base[129];
    __shared__ int cw[128];
    __shared__ int esl[CAP_H];
    __shared__ float a2[128 * 17];     // padded
    __shared__ float w2[H_MID * C_OUT];
    __shared__ float b2l[C_OUT];
    int b = blockIdx.x, t = threadIdx.x;
    int i0 = b * EBLK;
    int bb = hist[i0] + part[i0 >> 9];
    int bn = (b + 1 < NBUK) ? (hist[i0 + EBLK] + part[(i0 + EBLK) >> 9]) : N_EDGES;
    int ecnt = bn - bb;
    int n0 = b * 128;
    if (t < H_MID * C_OUT) w2[t] = W2[t];
    if (t >= 1024 - C_OUT) b2l[t - (1024 - C_OUT)] = b2[t - (1024 - C_OUT)];
    if (t < 128) {
        int lb = rp[n0 + t] - bb;
        base[t] = lb;
        cw[t] = lb;
    }
    if (t == 128) base[128] = ecnt;
    __syncthreads();
    int g = t >> 4, j = t & 15;
    if (ecnt <= CAP_H) {
        for (int i = t; i < ecnt; i += 1024) {
            int v = __builtin_nontemporal_load(eb + bb + i);
            int r = atomicAdd(&cw[v >> 17], 1);
            esl[r] = v & SRC_MASK;
        }
        __syncthreads();
        for (int nd = g; nd < 128; nd += 64) {
            int node = n0 + nd;
            float dv = (node < N_NODES) ? dinv[node] : 0.f;
            int beg = base[nd], end = base[nd + 1];
            float acc = (node < N_NODES) ? __half2float(r1p[(size_t)node * H_MID + j]) : 0.f;
            int e = beg;
            for (; e + 8 <= end; e += 8) {
                int s0 = esl[e],     s1 = esl[e + 1], s2 = esl[e + 2], s3 = esl[e + 3];
                int s4 = esl[e + 4], s5 = esl[e + 5], s6 = esl[e + 6], s7 = esl[e + 7];
                acc += __half2float(r1p[(size_t)s0 * H_MID + j])
                     + __half2float(r1p[(size_t)s1 * H_MID + j])
                     + __half2float(r1p[(size_t)s2 * H_MID + j])
                     + __half2float(r1p[(size_t)s3 * H_MID + j])
                     + __half2float(r1p[(size_t)s4 * H_MID + j])
                     + __half2float(r1p[(size_t)s5 * H_MID + j])
                     + __half2float(r1p[(size_t)s6 * H_MID + j])
                     + __half2float(r1p[(size_t)s7 * H_MID + j]);
            }
            for (; e < end; ++e) acc += __half2float(r1p[(size_t)esl[e] * H_MID + j]);
            a2[nd * 17 + j] = dv * acc;                  // agg2
        }
    } else {
        for (int nd = g; nd < 128; nd += 64) {
            int node = n0 + nd;
            float dv = (node < N_NODES) ? dinv[node] : 0.f;
            float acc = (node < N_NODES) ? __half2float(r1p[(size_t)node * H_MID + j]) : 0.f;
            for (int i = 0; i < ecnt; ++i) {
                int v = eb[bb + i];
                if ((v >> 17) == nd)
                    acc += __half2float(r1p[(size_t)(v & SRC_MASK) * H_MID + j]);
            }
            a2[nd * 17 + j] = dv * acc;
        }
    }
    __syncthreads();
    for (int idx = t; idx < 128 * C_OUT; idx += 1024) {
        int nd = idx / C_OUT, c = idx - nd * C_OUT;
        int node = n0 + nd;
        if (node < N_NODES) {
            float s = b2l[c];
#pragma unroll
            for (int jj = 0; jj < H_MID; ++jj) s += a2[nd * 17 + jj] * w2[jj * C_OUT + c];
            __builtin_nontemporal_store(s, &out[(size_t)node * C_OUT + c]);
        }
    }
}

extern "C" void kernel_launch(void* const* d_in, const int* in_sizes, int n_in,
                              void* d_out, int out_size, void* d_ws, size_t ws_size,
                              hipStream_t stream) {
    const float* x  = (const float*)d_in[0];
    const int*   ei = (const int*)d_in[1];     // [2, E]: row 0 = src, row 1 = dst
    const float* W1 = (const float*)d_in[2];
    const float* b1 = (const float*)d_in[3];
    const float* W2 = (const float*)d_in[4];
    const float* b2 = (const float*)d_in[5];
    float* out = (float*)d_out;

    const int* src = ei;
    const int* dst = ei + N_EDGES;

    // ws layout (4B units), ~21.3 MiB -- all in d_ws (csrg2 reads eb while
    // writing out, so d_out is not used as scratch):
    //   rp[100352] | dinv[100352] | h1p[NSTRIDE*16 half] | r1p[same] |
    //   eb[3.2M] | hist[306176] | part[1024]
    int* rp     = (int*)d_ws;
    float* dinv = (float*)(rp + NSTRIDE);
    __half* h1p = (__half*)(dinv + NSTRIDE);
    __half* r1p = h1p + (size_t)NSTRIDE * H_MID;
    int* eb     = (int*)(r1p + (size_t)NSTRIDE * H_MID);
    int* hist   = eb + N_EDGES;
    int* part   = hist + 306176;

    k_hist <<<EBLK, 1024, 0, stream>>>(dst, hist);
    k_scanA<<<NPART, 512, 0, stream>>>(hist, part);
    k_scanB<<<1, 1024, 0, stream>>>(part);
    k_part <<<EBLK, 1024, 0, stream>>>(src, dst, hist, part, eb);
    k_degrp<<<NBUK, 512, 0, stream>>>(hist, part, eb, rp, dinv);
    k_gemm1<<<N_NODES / 16, 256, 0, stream>>>(x, W1, dinv, h1p);
    k_csrg1<<<NBUK, 1024, 0, stream>>>(hist, part, eb, rp, dinv, h1p, b1, r1p);
    k_csrg2<<<NBUK, 1024, 0, stream>>>(hist, part, eb, rp, dinv, r1p, W2, b2, out);
}